// Round 3
// baseline (864.961 us; speedup 1.0000x reference)
//
#include <hip/hip_runtime.h>

#define NN 100000
#define NE 3200000
#define FIN 64
#define FH 32
#define FO 5
#define NB 1000      // dst buckets
#define NPB 100      // nodes per bucket
#define GC 512       // blocks for count/fill passes
#define EPB (NE/GC)  // 6250 edges per count/fill block

// ---------- edge dtype detect (int64 vs int32) ----------
__global__ void k_detect(const int* __restrict__ ei, int* __restrict__ flag) {
    int v = ei[2 * (int)threadIdx.x + 1];
    unsigned long long m = __ballot(v == 0);
    if (threadIdx.x == 0) flag[0] = (m == ~0ULL) ? 1 : 0;
}

// ---------- pass A: per-block LDS histogram of dst buckets ----------
__global__ void k_countA(const int* __restrict__ ei, int* __restrict__ cntRM,
                         const int* __restrict__ flag) {
    __shared__ int h[NB];
    int tid = threadIdx.x, g = blockIdx.x;
    for (int i = tid; i < NB; i += 256) h[i] = 0;
    __syncthreads();
    int is64 = flag[0];
    int base = g * EPB;
    for (int e = base + tid; e < base + EPB; e += 256) {
        int dst = is64 ? ei[2 * NE + 2 * e] : ei[NE + e];
        atomicAdd(&h[dst / NPB], 1);
    }
    __syncthreads();
    for (int i = tid; i < NB; i += 256) cntRM[g * NB + i] = h[i];
}

// ---------- pass B1: per-bucket exclusive scan over blocks ----------
__global__ void k_scanCol(const int* __restrict__ cntRM, int* __restrict__ offsT,
                          int* __restrict__ total) {
    __shared__ int pair[256];
    int b = blockIdx.x, t = threadIdx.x;
    int a0 = cntRM[(2 * t) * NB + b];
    int a1 = cntRM[(2 * t + 1) * NB + b];
    pair[t] = a0 + a1;
    __syncthreads();
    for (int off = 1; off < 256; off <<= 1) {
        int v = (t >= off) ? pair[t - off] : 0;
        __syncthreads();
        pair[t] += v;
        __syncthreads();
    }
    int excl = pair[t] - (a0 + a1);
    offsT[b * GC + 2 * t] = excl;
    offsT[b * GC + 2 * t + 1] = excl + a0;
    if (t == 255) total[b] = pair[255];
}

// ---------- pass B2: scan bucket totals -> bucket bases ----------
__global__ void k_scanTot(const int* __restrict__ total, int* __restrict__ bbase) {
    __shared__ int s[1024];
    int t = threadIdx.x;
    int v = (t < NB) ? total[t] : 0;
    s[t] = v;
    __syncthreads();
    for (int off = 1; off < 1024; off <<= 1) {
        int x = (t >= off) ? s[t - off] : 0;
        __syncthreads();
        s[t] += x;
        __syncthreads();
    }
    if (t < NB) bbase[t] = s[t] - v;
    if (t == NB - 1) bbase[NB] = s[t];
}

// ---------- pass C: scatter edges into bucket-grouped edata ----------
// edata[i].x = src | (dst_local << 20); edata[i].y = bits(w)
__global__ void k_fillC(const int* __restrict__ ei, const float* __restrict__ w,
                        const int* __restrict__ offsT, const int* __restrict__ bbase,
                        int2* __restrict__ edata, const int* __restrict__ flag) {
    __shared__ int offs[NB];
    int tid = threadIdx.x, g = blockIdx.x;
    for (int b = tid; b < NB; b += 256) offs[b] = bbase[b] + offsT[b * GC + g];
    __syncthreads();
    int is64 = flag[0];
    int base = g * EPB;
    for (int e = base + tid; e < base + EPB; e += 256) {
        int src, dst;
        if (is64) { src = ei[2 * e]; dst = ei[2 * NE + 2 * e]; }
        else      { src = ei[e];     dst = ei[NE + e]; }
        int b = dst / NPB;
        int dloc = dst - b * NPB;
        int pos = atomicAdd(&offs[b], 1);
        edata[pos] = make_int2(src | (dloc << 20), __float_as_int(w[e]));
    }
}

// ---------- dinv per bucket: rsqrt(1 + sum of in-edge weights) ----------
__global__ void k_dinvB(const int* __restrict__ bbase, const int2* __restrict__ edata,
                        float* __restrict__ dinv) {
    __shared__ float deg[NPB];
    int b = blockIdx.x, tid = threadIdx.x;
    if (tid < NPB) deg[tid] = 0.f;
    __syncthreads();
    int s = bbase[b], t = bbase[b + 1];
    for (int i = s + tid; i < t; i += 256) {
        int2 e = edata[i];
        atomicAdd(&deg[e.x >> 20], __int_as_float(e.y));
    }
    __syncthreads();
    if (tid < NPB) dinv[b * NPB + tid] = rsqrtf(1.0f + deg[tid]);
}

// ---------- hs1[n,h] = dinv[n] * (x @ W1)[n,h] ----------
__global__ void k_gemm1(const float* __restrict__ x, const float* __restrict__ W1,
                        const float* __restrict__ dinv, float* __restrict__ hs1) {
    __shared__ float Ws[FIN * FH];  // 8 KB
    __shared__ float Xs[8 * FIN];   // 2 KB
    int tid = threadIdx.x;
    for (int i = tid; i < FIN * FH; i += 256) Ws[i] = W1[i];
    int row0 = blockIdx.x * 8;
    for (int i = tid; i < 8 * FIN; i += 256) {
        int r = i >> 6, f = i & 63;
        Xs[i] = x[(row0 + r) * FIN + f];
    }
    __syncthreads();
    int h = tid & 31, r = tid >> 5;
    int n = row0 + r;
    float acc = 0.f;
#pragma unroll
    for (int f = 0; f < FIN; ++f) acc += Xs[r * FIN + f] * Ws[f * FH + h];
    hs1[n * FH + h] = dinv[n] * acc;
}

// ---------- pull layer 1 per bucket: LDS tile accumulate + bias + relu ----------
__global__ void k_pull1(const int* __restrict__ bbase, const int2* __restrict__ edata,
                        const float* __restrict__ hs1, const float* __restrict__ dinv,
                        const float* __restrict__ b1, float* __restrict__ x1out) {
    __shared__ float acc[NPB * FH];  // 12.8 KB
    int b = blockIdx.x, tid = threadIdx.x;
    for (int i = tid; i < NPB * FH; i += 256) acc[i] = 0.f;
    __syncthreads();
    int s = bbase[b], t = bbase[b + 1];
    int h = tid & 31, slot = tid >> 5;
    for (int i = s + slot; i < t; i += 8) {
        int2 e = edata[i];
        float v = __int_as_float(e.y) * hs1[(e.x & 0xFFFFF) * FH + h];
        atomicAdd(&acc[(e.x >> 20) * FH + h], v);
    }
    __syncthreads();
    for (int j = tid; j < NPB * FH; j += 256) {
        int n = b * NPB + (j >> 5);
        int hh = j & 31;
        float v = dinv[n] * (acc[j] + hs1[n * FH + hh]) + b1[hh];
        x1out[n * FH + hh] = (v > 0.f) ? v : 0.f;
    }
}

// ---------- hs2[n,c] = dinv[n] * (x1 @ W2)[n,c] ----------
__global__ void k_gemm2(const float* __restrict__ x1, const float* __restrict__ W2,
                        const float* __restrict__ dinv, float* __restrict__ hs2) {
    __shared__ float Ws[FH * FO];
    int tid = threadIdx.x;
    if (tid < FH * FO) Ws[tid] = W2[tid];
    __syncthreads();
    int n = blockIdx.x * 256 + tid;
    if (n >= NN) return;
    float a0 = 0.f, a1 = 0.f, a2 = 0.f, a3 = 0.f, a4 = 0.f;
    const float* xr = x1 + n * FH;
#pragma unroll
    for (int h = 0; h < FH; ++h) {
        float xv = xr[h];
        a0 += xv * Ws[h * FO + 0];
        a1 += xv * Ws[h * FO + 1];
        a2 += xv * Ws[h * FO + 2];
        a3 += xv * Ws[h * FO + 3];
        a4 += xv * Ws[h * FO + 4];
    }
    float di = dinv[n];
    float* o = hs2 + n * FO;
    o[0] = di * a0; o[1] = di * a1; o[2] = di * a2; o[3] = di * a3; o[4] = di * a4;
}

// ---------- pull layer 2 per bucket ----------
__global__ void k_pull2(const int* __restrict__ bbase, const int2* __restrict__ edata,
                        const float* __restrict__ hs2, const float* __restrict__ dinv,
                        const float* __restrict__ b2, float* __restrict__ out) {
    __shared__ float acc[NPB * 8];  // pad FO->8
    int b = blockIdx.x, tid = threadIdx.x;
    for (int i = tid; i < NPB * 8; i += 256) acc[i] = 0.f;
    __syncthreads();
    int s = bbase[b], t = bbase[b + 1];
    int c = tid & 7, slot = tid >> 3;
    for (int i = s + slot; i < t; i += 32) {
        int2 e = edata[i];
        if (c < FO) {
            float v = __int_as_float(e.y) * hs2[(e.x & 0xFFFFF) * FO + c];
            atomicAdd(&acc[(e.x >> 20) * 8 + c], v);
        }
    }
    __syncthreads();
    for (int j = tid; j < NPB * FO; j += 256) {
        int n = b * NPB + j / FO;
        int cc = j % FO;
        out[n * FO + cc] = dinv[n] * (acc[(j / FO) * 8 + cc] + hs2[n * FO + cc]) + b2[cc];
    }
}

extern "C" void kernel_launch(void* const* d_in, const int* in_sizes, int n_in,
                              void* d_out, int out_size, void* d_ws, size_t ws_size,
                              hipStream_t stream) {
    const float* x  = (const float*)d_in[0];
    const int*   ei = (const int*)d_in[1];
    const float* w  = (const float*)d_in[2];
    const float* W1 = (const float*)d_in[3];
    const float* b1 = (const float*)d_in[4];
    const float* W2 = (const float*)d_in[5];
    const float* b2 = (const float*)d_in[6];
    float* out = (float*)d_out;  // x2 in [0,5N), x1 in [5N,37N)
    float* ws  = (float*)d_ws;

    // workspace layout (4B units) — cntRM/offsT overlap hs1 (dead until gemm1)
    int2*  edata  = (int2*)ws;                      // [0, 6.4M) ints
    float* dinv   = ws + 6400000;                   // 100k
    float* hs1    = ws + 6500000;                   // 3.2M
    float* hs2    = ws + 9700000;                   // 500k
    int*   bbase  = (int*)(ws + 10200000);          // NB+1
    int*   flag   = (int*)(ws + 10200000 + 1024);   // 1
    int*   total  = (int*)(ws + 10200000 + 2048);   // NB
    int*   cntRM  = (int*)hs1;                      // GC*NB = 512k (overlap)
    int*   offsT  = (int*)hs1 + 512000;             // GC*NB = 512k (overlap)

    float* x1 = out + NN * FO;

    k_detect<<<1, 64, 0, stream>>>(ei, flag);
    k_countA<<<GC, 256, 0, stream>>>(ei, cntRM, flag);
    k_scanCol<<<NB, 256, 0, stream>>>(cntRM, offsT, total);
    k_scanTot<<<1, 1024, 0, stream>>>(total, bbase);
    k_fillC<<<GC, 256, 0, stream>>>(ei, w, offsT, bbase, edata, flag);
    k_dinvB<<<NB, 256, 0, stream>>>(bbase, edata, dinv);
    k_gemm1<<<NN / 8, 256, 0, stream>>>(x, W1, dinv, hs1);
    k_pull1<<<NB, 256, 0, stream>>>(bbase, edata, hs1, dinv, b1, x1);
    k_gemm2<<<(NN + 255) / 256, 256, 0, stream>>>(x1, W2, dinv, hs2);
    k_pull2<<<NB, 256, 0, stream>>>(bbase, edata, hs2, dinv, b2, out);
}

// Round 4
// 324.295 us; speedup vs baseline: 2.6672x; 2.6672x over previous
//
#include <hip/hip_runtime.h>

#define NN 100000
#define NE 3200000
#define FIN 64
#define FH 32
#define FO 5
#define NB 500       // dst buckets
#define NPB 200      // nodes per bucket (NB*NPB == NN)
#define GC 512       // blocks for count/fill passes
#define EPB (NE/GC)  // 6250 edges per count/fill block

// ---------- edge dtype detect (int64 vs int32) ----------
__global__ void k_detect(const int* __restrict__ ei, int* __restrict__ flag) {
    int v = ei[2 * (int)threadIdx.x + 1];
    unsigned long long m = __ballot(v == 0);
    if (threadIdx.x == 0) flag[0] = (m == ~0ULL) ? 1 : 0;
}

// ---------- pass A: per-block LDS histogram of dst buckets ----------
__global__ void k_countA(const int* __restrict__ ei, int* __restrict__ cntRM,
                         const int* __restrict__ flag) {
    __shared__ int h[NB];
    int tid = threadIdx.x, g = blockIdx.x;
    for (int i = tid; i < NB; i += 256) h[i] = 0;
    __syncthreads();
    int is64 = flag[0];
    int base = g * EPB;
    for (int e = base + tid; e < base + EPB; e += 256) {
        int dst = is64 ? ei[2 * NE + 2 * e] : ei[NE + e];
        atomicAdd(&h[dst / NPB], 1);
    }
    __syncthreads();
    for (int i = tid; i < NB; i += 256) cntRM[g * NB + i] = h[i];
}

// ---------- pass B1: per-bucket exclusive scan over fill blocks ----------
__global__ void k_scanCol(const int* __restrict__ cntRM, int* __restrict__ offsT,
                          int* __restrict__ total) {
    __shared__ int pair[256];
    int b = blockIdx.x, t = threadIdx.x;
    int a0 = cntRM[(2 * t) * NB + b];
    int a1 = cntRM[(2 * t + 1) * NB + b];
    pair[t] = a0 + a1;
    __syncthreads();
    for (int off = 1; off < 256; off <<= 1) {
        int v = (t >= off) ? pair[t - off] : 0;
        __syncthreads();
        pair[t] += v;
        __syncthreads();
    }
    int excl = pair[t] - (a0 + a1);
    offsT[b * GC + 2 * t] = excl;
    offsT[b * GC + 2 * t + 1] = excl + a0;
    if (t == 255) total[b] = pair[255];
}

// ---------- pass B2: scan bucket totals -> bucket bases ----------
__global__ void k_scanTot(const int* __restrict__ total, int* __restrict__ bbase) {
    __shared__ int s[512];
    int t = threadIdx.x;
    int v = (t < NB) ? total[t] : 0;
    s[t] = v;
    __syncthreads();
    for (int off = 1; off < 512; off <<= 1) {
        int x = (t >= off) ? s[t - off] : 0;
        __syncthreads();
        s[t] += x;
        __syncthreads();
    }
    if (t < NB) bbase[t] = s[t] - v;
    if (t == NB - 1) bbase[NB] = s[t];
}

// ---------- pass C: scatter edges into bucket-grouped edata ----------
// edata[i].x = src | (dst_local << 20); edata[i].y = bits(w)
__global__ void k_fillC(const int* __restrict__ ei, const float* __restrict__ w,
                        const int* __restrict__ offsT, const int* __restrict__ bbase,
                        int2* __restrict__ edata, const int* __restrict__ flag) {
    __shared__ int offs[NB];
    int tid = threadIdx.x, g = blockIdx.x;
    for (int b = tid; b < NB; b += 256) offs[b] = bbase[b] + offsT[b * GC + g];
    __syncthreads();
    int is64 = flag[0];
    int base = g * EPB;
    for (int e = base + tid; e < base + EPB; e += 256) {
        int src, dst;
        if (is64) { src = ei[2 * e]; dst = ei[2 * NE + 2 * e]; }
        else      { src = ei[e];     dst = ei[NE + e]; }
        int b = dst / NPB;
        int dloc = dst - b * NPB;
        int pos = atomicAdd(&offs[b], 1);
        edata[pos] = make_int2(src | (dloc << 20), __float_as_int(w[e]));
    }
}

// ---------- per-bucket counting sort -> per-node CSR + dinv ----------
__global__ void k_nodecsr(const int* __restrict__ bbase, const int2* __restrict__ edata,
                          int2* __restrict__ edata2, int* __restrict__ rowptr,
                          float* __restrict__ dinv) {
    __shared__ int cnt[NPB];
    __shared__ int offs[NPB];
    __shared__ float deg[NPB];
    __shared__ int sc[256];
    int b = blockIdx.x, tid = threadIdx.x;
    if (tid < NPB) { cnt[tid] = 0; deg[tid] = 0.f; }
    __syncthreads();
    int s = bbase[b], t = bbase[b + 1];
    for (int i = s + tid; i < t; i += 256) {
        int2 e = edata[i];
        int dloc = e.x >> 20;
        atomicAdd(&cnt[dloc], 1);
        atomicAdd(&deg[dloc], __int_as_float(e.y));
    }
    __syncthreads();
    // exclusive scan of cnt[0..NPB) over 256 slots
    int v = (tid < NPB) ? cnt[tid] : 0;
    sc[tid] = v;
    __syncthreads();
    for (int off = 1; off < 256; off <<= 1) {
        int x = (tid >= off) ? sc[tid - off] : 0;
        __syncthreads();
        sc[tid] += x;
        __syncthreads();
    }
    if (tid < NPB) {
        int base = s + sc[tid] - v;
        offs[tid] = base;
        rowptr[b * NPB + tid] = base;
        dinv[b * NPB + tid] = rsqrtf(1.0f + deg[tid]);
    }
    if (b == NB - 1 && tid == 0) rowptr[NN] = t;
    __syncthreads();
    for (int i = s + tid; i < t; i += 256) {
        int2 e = edata[i];
        int dloc = e.x >> 20;
        int pos = atomicAdd(&offs[dloc], 1);
        edata2[pos] = make_int2(e.x & 0xFFFFF, e.y);
    }
}

// ---------- hs1[n,h] = dinv[n] * (x @ W1)[n,h] ----------
__global__ void k_gemm1(const float* __restrict__ x, const float* __restrict__ W1,
                        const float* __restrict__ dinv, float* __restrict__ hs1) {
    __shared__ float Ws[FIN * FH];  // 8 KB
    __shared__ float Xs[8 * FIN];   // 2 KB
    int tid = threadIdx.x;
    for (int i = tid; i < FIN * FH; i += 256) Ws[i] = W1[i];
    int row0 = blockIdx.x * 8;
    for (int i = tid; i < 8 * FIN; i += 256) {
        int r = i >> 6, f = i & 63;
        Xs[i] = x[(row0 + r) * FIN + f];
    }
    __syncthreads();
    int h = tid & 31, r = tid >> 5;
    int n = row0 + r;
    float acc = 0.f;
#pragma unroll
    for (int f = 0; f < FIN; ++f) acc += Xs[r * FIN + f] * Ws[f * FH + h];
    hs1[n * FH + h] = dinv[n] * acc;
}

// ---------- pull layer 1: per-node, 32 lanes/node, 4-way edge ILP ----------
__global__ void k_pull1(const int* __restrict__ rowptr, const int2* __restrict__ ed,
                        const float* __restrict__ hs1, const float* __restrict__ dinv,
                        const float* __restrict__ b1, float* __restrict__ x1out) {
    int tid = threadIdx.x;
    int h = tid & 31;
    int n = blockIdx.x * 8 + (tid >> 5);
    int s = rowptr[n], t = rowptr[n + 1];
    float acc = hs1[n * FH + h];  // self-loop (w=1)
    int i = s;
    for (; i + 4 <= t; i += 4) {
        int2 e0 = ed[i], e1 = ed[i + 1], e2 = ed[i + 2], e3 = ed[i + 3];
        float v0 = hs1[e0.x * FH + h];
        float v1 = hs1[e1.x * FH + h];
        float v2 = hs1[e2.x * FH + h];
        float v3 = hs1[e3.x * FH + h];
        acc += __int_as_float(e0.y) * v0;
        acc += __int_as_float(e1.y) * v1;
        acc += __int_as_float(e2.y) * v2;
        acc += __int_as_float(e3.y) * v3;
    }
    for (; i < t; ++i) {
        int2 e = ed[i];
        acc += __int_as_float(e.y) * hs1[e.x * FH + h];
    }
    float v = dinv[n] * acc + b1[h];
    x1out[n * FH + h] = (v > 0.f) ? v : 0.f;
}

// ---------- hs2[n,c] = dinv[n] * (x1 @ W2)[n,c] ----------
__global__ void k_gemm2(const float* __restrict__ x1, const float* __restrict__ W2,
                        const float* __restrict__ dinv, float* __restrict__ hs2) {
    __shared__ float Ws[FH * FO];
    int tid = threadIdx.x;
    if (tid < FH * FO) Ws[tid] = W2[tid];
    __syncthreads();
    int n = blockIdx.x * 256 + tid;
    if (n >= NN) return;
    float a0 = 0.f, a1 = 0.f, a2 = 0.f, a3 = 0.f, a4 = 0.f;
    const float* xr = x1 + n * FH;
#pragma unroll
    for (int h = 0; h < FH; ++h) {
        float xv = xr[h];
        a0 += xv * Ws[h * FO + 0];
        a1 += xv * Ws[h * FO + 1];
        a2 += xv * Ws[h * FO + 2];
        a3 += xv * Ws[h * FO + 3];
        a4 += xv * Ws[h * FO + 4];
    }
    float di = dinv[n];
    float* o = hs2 + n * FO;
    o[0] = di * a0; o[1] = di * a1; o[2] = di * a2; o[3] = di * a3; o[4] = di * a4;
}

// ---------- pull layer 2: per-node, 8 lanes/node, 4-way edge ILP ----------
__global__ void k_pull2(const int* __restrict__ rowptr, const int2* __restrict__ ed,
                        const float* __restrict__ hs2, const float* __restrict__ dinv,
                        const float* __restrict__ b2, float* __restrict__ out) {
    int tid = threadIdx.x;
    int c = tid & 7;
    int cm = (c < FO) ? c : 0;
    int n = blockIdx.x * 32 + (tid >> 3);
    int s = rowptr[n], t = rowptr[n + 1];
    float acc = hs2[n * FO + cm];  // self-loop
    int i = s;
    for (; i + 4 <= t; i += 4) {
        int2 e0 = ed[i], e1 = ed[i + 1], e2 = ed[i + 2], e3 = ed[i + 3];
        float v0 = hs2[e0.x * FO + cm];
        float v1 = hs2[e1.x * FO + cm];
        float v2 = hs2[e2.x * FO + cm];
        float v3 = hs2[e3.x * FO + cm];
        acc += __int_as_float(e0.y) * v0;
        acc += __int_as_float(e1.y) * v1;
        acc += __int_as_float(e2.y) * v2;
        acc += __int_as_float(e3.y) * v3;
    }
    for (; i < t; ++i) {
        int2 e = ed[i];
        acc += __int_as_float(e.y) * hs2[e.x * FO + cm];
    }
    if (c < FO) out[n * FO + c] = dinv[n] * acc + b2[c];
}

extern "C" void kernel_launch(void* const* d_in, const int* in_sizes, int n_in,
                              void* d_out, int out_size, void* d_ws, size_t ws_size,
                              hipStream_t stream) {
    const float* x  = (const float*)d_in[0];
    const int*   ei = (const int*)d_in[1];
    const float* w  = (const float*)d_in[2];
    const float* W1 = (const float*)d_in[3];
    const float* b1 = (const float*)d_in[4];
    const float* W2 = (const float*)d_in[5];
    const float* b2 = (const float*)d_in[6];
    float* out = (float*)d_out;  // x2 in [0,5N), x1 in [5N,37N)
    float* ws  = (float*)d_ws;

    // workspace layout (4B words), ~52 MB total:
    // region A [0, 6.4M): edata during build; hs1 [0,3.2M) + hs2 [3.2M,3.7M) after
    // region B [6.4M, 12.8M): cntRM/offsT during build; edata2 after (persists)
    int2*  edata  = (int2*)ws;                       // 3.2M int2
    int*   cntRM  = (int*)(ws + 6400000);            // GC*NB = 256000
    int*   offsT  = (int*)(ws + 6400000 + 256000);   // GC*NB = 256000
    int2*  edata2 = (int2*)(ws + 6400000);           // 3.2M int2 (after build)
    float* hs1    = ws;                              // 3.2M (edata dead by gemm1)
    float* hs2    = ws + 3200000;                    // 500k
    float* dinv   = ws + 12800000;                   // 100k
    int*   rowptr = (int*)(ws + 12900000);           // NN+1
    int*   bbase  = (int*)(ws + 13000064);           // NB+1
    int*   total  = (int*)(ws + 13000704);           // NB
    int*   flag   = (int*)(ws + 13001280);           // 1

    float* x1 = out + NN * FO;

    k_detect<<<1, 64, 0, stream>>>(ei, flag);
    k_countA<<<GC, 256, 0, stream>>>(ei, cntRM, flag);
    k_scanCol<<<NB, 256, 0, stream>>>(cntRM, offsT, total);
    k_scanTot<<<1, 512, 0, stream>>>(total, bbase);
    k_fillC<<<GC, 256, 0, stream>>>(ei, w, offsT, bbase, edata, flag);
    k_nodecsr<<<NB, 256, 0, stream>>>(bbase, edata, edata2, rowptr, dinv);
    k_gemm1<<<NN / 8, 256, 0, stream>>>(x, W1, dinv, hs1);
    k_pull1<<<NN / 8, 256, 0, stream>>>(rowptr, edata2, hs1, dinv, b1, x1);
    k_gemm2<<<(NN + 255) / 256, 256, 0, stream>>>(x1, W2, dinv, hs2);
    k_pull2<<<NN / 32, 256, 0, stream>>>(rowptr, edata2, hs2, dinv, b2, out);
}

// Round 5
// 300.396 us; speedup vs baseline: 2.8794x; 1.0796x over previous
//
#include <hip/hip_runtime.h>

#define NN 100000
#define NE 3200000
#define FIN 64
#define FH 32
#define FO 5
#define NB 500       // dst buckets
#define NPB 200      // nodes per bucket (NB*NPB == NN)
#define GC 512       // blocks for count/fill passes
#define EPB (NE/GC)  // 6250 edges per count/fill block
#define CAP 7168     // LDS edge staging capacity in k_nodecsr (mean 6400, sigma~80)

__device__ __forceinline__ int detect64(const int* __restrict__ ei, int* sflag, int tid) {
    if (tid < 64) {
        int v = ei[2 * tid + 1];
        unsigned long long m = __ballot(v == 0);
        if (tid == 0) *sflag = (m == ~0ULL) ? 1 : 0;
    }
    __syncthreads();
    return *sflag;
}

__device__ __forceinline__ unsigned bf16r(float f) {  // fp32 -> bf16 bits, RNE
    unsigned u = __float_as_uint(f);
    return (u + 0x7FFFu + ((u >> 16) & 1u)) >> 16;
}
__device__ __forceinline__ float blo(unsigned u) { return __uint_as_float(u << 16); }
__device__ __forceinline__ float bhi(unsigned u) { return __uint_as_float(u & 0xFFFF0000u); }

// ---------- pass A: per-block LDS histogram of dst buckets ----------
__global__ void k_countA(const int* __restrict__ ei, int* __restrict__ cntRM) {
    __shared__ int h[NB];
    __shared__ int sflag;
    int tid = threadIdx.x, g = blockIdx.x;
    for (int i = tid; i < NB; i += 256) h[i] = 0;
    int is64 = detect64(ei, &sflag, tid);
    __syncthreads();
    int base = g * EPB;
    for (int e = base + tid; e < base + EPB; e += 256) {
        int dst = is64 ? ei[2 * NE + 2 * e] : ei[NE + e];
        atomicAdd(&h[dst / NPB], 1);
    }
    __syncthreads();
    for (int i = tid; i < NB; i += 256) cntRM[g * NB + i] = h[i];
}

// ---------- pass B1: per-bucket exclusive scan over fill blocks ----------
__global__ void k_scanCol(const int* __restrict__ cntRM, int* __restrict__ offsT,
                          int* __restrict__ total) {
    __shared__ int pair[256];
    int b = blockIdx.x, t = threadIdx.x;
    int a0 = cntRM[(2 * t) * NB + b];
    int a1 = cntRM[(2 * t + 1) * NB + b];
    pair[t] = a0 + a1;
    __syncthreads();
    for (int off = 1; off < 256; off <<= 1) {
        int v = (t >= off) ? pair[t - off] : 0;
        __syncthreads();
        pair[t] += v;
        __syncthreads();
    }
    int excl = pair[t] - (a0 + a1);
    offsT[b * GC + 2 * t] = excl;
    offsT[b * GC + 2 * t + 1] = excl + a0;
    if (t == 255) total[b] = pair[255];
}

// ---------- pass B2: scan bucket totals -> bucket bases ----------
__global__ void k_scanTot(const int* __restrict__ total, int* __restrict__ bbase) {
    __shared__ int s[512];
    int t = threadIdx.x;
    int v = (t < NB) ? total[t] : 0;
    s[t] = v;
    __syncthreads();
    for (int off = 1; off < 512; off <<= 1) {
        int x = (t >= off) ? s[t - off] : 0;
        __syncthreads();
        s[t] += x;
        __syncthreads();
    }
    if (t < NB) bbase[t] = s[t] - v;
    if (t == NB - 1) bbase[NB] = s[t];
}

// ---------- pass C: scatter edges into bucket-grouped edata ----------
// edata[i].x = src | (dst_local << 20); edata[i].y = bits(w)
__global__ void k_fillC(const int* __restrict__ ei, const float* __restrict__ w,
                        const int* __restrict__ offsT, const int* __restrict__ bbase,
                        int2* __restrict__ edata) {
    __shared__ int offs[NB];
    __shared__ int sflag;
    int tid = threadIdx.x, g = blockIdx.x;
    for (int b = tid; b < NB; b += 256) offs[b] = bbase[b] + offsT[b * GC + g];
    int is64 = detect64(ei, &sflag, tid);
    __syncthreads();
    int base = g * EPB;
    for (int e = base + tid; e < base + EPB; e += 256) {
        int src, dst;
        if (is64) { src = ei[2 * e]; dst = ei[2 * NE + 2 * e]; }
        else      { src = ei[e];     dst = ei[NE + e]; }
        int b = dst / NPB;
        int dloc = dst - b * NPB;
        int pos = atomicAdd(&offs[b], 1);
        edata[pos] = make_int2(src | (dloc << 20), __float_as_int(w[e]));
    }
}

// ---------- per-bucket counting sort (LDS-staged) -> per-node CSR + dinv ----------
__global__ void k_nodecsr(const int* __restrict__ bbase, const int2* __restrict__ edata,
                          int2* __restrict__ edata2, int* __restrict__ rowptr,
                          float* __restrict__ dinv) {
    __shared__ int2 stage[CAP];   // 57.3 KB
    __shared__ int cnt[NPB];
    __shared__ int offs[NPB];
    __shared__ float deg[NPB];
    __shared__ int sc[256];
    int b = blockIdx.x, tid = threadIdx.x;
    if (tid < NPB) { cnt[tid] = 0; deg[tid] = 0.f; }
    __syncthreads();
    int s = bbase[b], t = bbase[b + 1];
    int m = t - s; if (m > CAP) m = CAP;
    for (int i = tid; i < m; i += 256) {
        int2 e = edata[s + i];
        stage[i] = e;
        int dloc = e.x >> 20;
        atomicAdd(&cnt[dloc], 1);
        atomicAdd(&deg[dloc], __int_as_float(e.y));
    }
    for (int i = s + CAP + tid; i < t; i += 256) {  // overflow fallback (rare)
        int2 e = edata[i];
        atomicAdd(&cnt[e.x >> 20], 1);
        atomicAdd(&deg[e.x >> 20], __int_as_float(e.y));
    }
    __syncthreads();
    int v = (tid < NPB) ? cnt[tid] : 0;
    sc[tid] = v;
    __syncthreads();
    for (int off = 1; off < 256; off <<= 1) {
        int x = (tid >= off) ? sc[tid - off] : 0;
        __syncthreads();
        sc[tid] += x;
        __syncthreads();
    }
    if (tid < NPB) {
        int base = s + sc[tid] - v;
        offs[tid] = base;
        rowptr[b * NPB + tid] = base;
        dinv[b * NPB + tid] = rsqrtf(1.0f + deg[tid]);
    }
    if (b == NB - 1 && tid == 0) rowptr[NN] = t;
    __syncthreads();
    for (int i = tid; i < m; i += 256) {
        int2 e = stage[i];
        int pos = atomicAdd(&offs[e.x >> 20], 1);
        edata2[pos] = make_int2(e.x & 0xFFFFF, e.y);
    }
    for (int i = s + CAP + tid; i < t; i += 256) {
        int2 e = edata[i];
        int pos = atomicAdd(&offs[e.x >> 20], 1);
        edata2[pos] = make_int2(e.x & 0xFFFFF, e.y);
    }
}

// ---------- hs1b[n,l] = packed bf16 pair of dinv[n]*(x @ W1)[n, 2l:2l+2] ----------
__global__ void k_gemm1(const float* __restrict__ x, const float* __restrict__ W1,
                        const float* __restrict__ dinv, unsigned* __restrict__ hs1b) {
    __shared__ float Ws[FIN * FH];   // 8 KB
    __shared__ float Xs[16 * FIN];   // 4 KB
    int tid = threadIdx.x;
    for (int i = tid; i < FIN * FH; i += 256) Ws[i] = W1[i];
    int row0 = blockIdx.x * 16;
    for (int i = tid; i < 16 * FIN; i += 256) Xs[i] = x[row0 * FIN + i];
    __syncthreads();
    int l = tid & 15, r = tid >> 4;
    int n = row0 + r;
    float a0 = 0.f, a1 = 0.f;
    const float* xr = &Xs[r * FIN];
#pragma unroll
    for (int f = 0; f < FIN; ++f) {
        float xv = xr[f];
        a0 += xv * Ws[f * FH + 2 * l];
        a1 += xv * Ws[f * FH + 2 * l + 1];
    }
    float di = dinv[n];
    hs1b[n * 16 + l] = bf16r(di * a0) | (bf16r(di * a1) << 16);
}

// ---------- pull layer 1 (bf16 gathers, 16 lanes/node, ILP4) + fused gemm2 ----------
__global__ void k_pull1(const int* __restrict__ rowptr, const int2* __restrict__ ed,
                        const unsigned* __restrict__ hs1b, const float* __restrict__ dinv,
                        const float* __restrict__ b1, const float* __restrict__ W2,
                        float* __restrict__ x1out, float* __restrict__ hs2) {
    __shared__ float Ws2[FH * FO];
    int tid = threadIdx.x;
    if (tid < FH * FO) Ws2[tid] = W2[tid];
    __syncthreads();
    int l = tid & 15;
    int n = blockIdx.x * 16 + (tid >> 4);
    int s = rowptr[n], t = rowptr[n + 1];
    unsigned su = hs1b[n * 16 + l];
    float a0 = blo(su), a1 = bhi(su);  // self-loop (w=1)
    int i = s;
    for (; i + 4 <= t; i += 4) {
        int2 e0 = ed[i], e1 = ed[i + 1], e2 = ed[i + 2], e3 = ed[i + 3];
        unsigned u0 = hs1b[e0.x * 16 + l];
        unsigned u1 = hs1b[e1.x * 16 + l];
        unsigned u2 = hs1b[e2.x * 16 + l];
        unsigned u3 = hs1b[e3.x * 16 + l];
        float w0 = __int_as_float(e0.y), w1 = __int_as_float(e1.y);
        float w2 = __int_as_float(e2.y), w3 = __int_as_float(e3.y);
        a0 += w0 * blo(u0); a1 += w0 * bhi(u0);
        a0 += w1 * blo(u1); a1 += w1 * bhi(u1);
        a0 += w2 * blo(u2); a1 += w2 * bhi(u2);
        a0 += w3 * blo(u3); a1 += w3 * bhi(u3);
    }
    for (; i < t; ++i) {
        int2 e = ed[i];
        unsigned u = hs1b[e.x * 16 + l];
        float we = __int_as_float(e.y);
        a0 += we * blo(u); a1 += we * bhi(u);
    }
    float di = dinv[n];
    float v0 = di * a0 + b1[2 * l];
    float v1 = di * a1 + b1[2 * l + 1];
    v0 = (v0 > 0.f) ? v0 : 0.f;
    v1 = (v1 > 0.f) ? v1 : 0.f;
    float2 st; st.x = v0; st.y = v1;
    *(float2*)&x1out[n * FH + 2 * l] = st;
    // fused layer-2 transform: hs2[n,c] = dinv[n] * sum_h x1[n,h]*W2[h,c]  (stride 8)
#pragma unroll
    for (int c = 0; c < FO; ++c) {
        float p = v0 * Ws2[(2 * l) * FO + c] + v1 * Ws2[(2 * l + 1) * FO + c];
        p += __shfl_xor(p, 1, 16);
        p += __shfl_xor(p, 2, 16);
        p += __shfl_xor(p, 4, 16);
        p += __shfl_xor(p, 8, 16);
        if (l == c) hs2[n * 8 + c] = di * p;
    }
}

// ---------- pull layer 2: per-node, 8 lanes/node, ILP4 (hs2 padded stride 8) ----------
__global__ void k_pull2(const int* __restrict__ rowptr, const int2* __restrict__ ed,
                        const float* __restrict__ hs2, const float* __restrict__ dinv,
                        const float* __restrict__ b2, float* __restrict__ out) {
    int tid = threadIdx.x;
    int c = tid & 7;
    int cm = (c < FO) ? c : 0;
    int n = blockIdx.x * 32 + (tid >> 3);
    int s = rowptr[n], t = rowptr[n + 1];
    float acc = hs2[n * 8 + cm];  // self-loop
    int i = s;
    for (; i + 4 <= t; i += 4) {
        int2 e0 = ed[i], e1 = ed[i + 1], e2 = ed[i + 2], e3 = ed[i + 3];
        float v0 = hs2[e0.x * 8 + cm];
        float v1 = hs2[e1.x * 8 + cm];
        float v2 = hs2[e2.x * 8 + cm];
        float v3 = hs2[e3.x * 8 + cm];
        acc += __int_as_float(e0.y) * v0;
        acc += __int_as_float(e1.y) * v1;
        acc += __int_as_float(e2.y) * v2;
        acc += __int_as_float(e3.y) * v3;
    }
    for (; i < t; ++i) {
        int2 e = ed[i];
        acc += __int_as_float(e.y) * hs2[e.x * 8 + cm];
    }
    if (c < FO) out[n * FO + c] = dinv[n] * acc + b2[c];
}

extern "C" void kernel_launch(void* const* d_in, const int* in_sizes, int n_in,
                              void* d_out, int out_size, void* d_ws, size_t ws_size,
                              hipStream_t stream) {
    const float* x  = (const float*)d_in[0];
    const int*   ei = (const int*)d_in[1];
    const float* w  = (const float*)d_in[2];
    const float* W1 = (const float*)d_in[3];
    const float* b1 = (const float*)d_in[4];
    const float* W2 = (const float*)d_in[5];
    const float* b2 = (const float*)d_in[6];
    float* out = (float*)d_out;  // x2 in [0,5N), x1 in [5N,37N)
    float* ws  = (float*)d_ws;

    // workspace layout (4B words), ~52 MB:
    // region A [0, 6.4M): edata during build; hs1b [0,1.6M) + hs2 [1.6M,2.4M) after
    // region B [6.4M, 12.8M): cntRM/offsT during build; edata2 after (persists)
    int2*     edata  = (int2*)ws;                       // 3.2M int2
    int*      cntRM  = (int*)(ws + 6400000);            // GC*NB = 256000
    int*      offsT  = (int*)(ws + 6400000 + 256000);   // GC*NB = 256000
    int2*     edata2 = (int2*)(ws + 6400000);           // 3.2M int2 (after build)
    unsigned* hs1b   = (unsigned*)ws;                   // 1.6M (edata dead by gemm1)
    float*    hs2    = ws + 1600000;                    // 800k (stride-8 padded)
    float*    dinv   = ws + 12800000;                   // 100k
    int*      rowptr = (int*)(ws + 12900000);           // NN+1
    int*      bbase  = (int*)(ws + 13000064);           // NB+1
    int*      total  = (int*)(ws + 13000704);           // NB

    float* x1 = out + NN * FO;

    k_countA<<<GC, 256, 0, stream>>>(ei, cntRM);
    k_scanCol<<<NB, 256, 0, stream>>>(cntRM, offsT, total);
    k_scanTot<<<1, 512, 0, stream>>>(total, bbase);
    k_fillC<<<GC, 256, 0, stream>>>(ei, w, offsT, bbase, edata);
    k_nodecsr<<<NB, 256, 0, stream>>>(bbase, edata, edata2, rowptr, dinv);
    k_gemm1<<<NN / 16, 256, 0, stream>>>(x, W1, dinv, hs1b);
    k_pull1<<<NN / 16, 256, 0, stream>>>(rowptr, edata2, hs1b, dinv, b1, W2, x1, hs2);
    k_pull2<<<NN / 32, 256, 0, stream>>>(rowptr, edata2, hs2, dinv, b2, out);
}

// Round 6
// 291.560 us; speedup vs baseline: 2.9667x; 1.0303x over previous
//
#include <hip/hip_runtime.h>

#define NN 100000
#define NE 3200000
#define FIN 64
#define FH 32
#define FO 5
#define NB 500       // dst buckets
#define NPB 200      // nodes per bucket (NB*NPB == NN)
#define GC 512       // blocks for count/fill passes
#define EPB (NE/GC)  // 6250 edges per count/fill block (exact)
#define CAP 7168     // LDS edge staging capacity in k_nodecsr (mean 6400, sigma~80)

__device__ __forceinline__ int detect64(const int* __restrict__ ei, int* sflag, int tid) {
    if (tid < 64) {
        int v = ei[2 * tid + 1];
        unsigned long long m = __ballot(v == 0);
        if (tid == 0) *sflag = (m == ~0ULL) ? 1 : 0;
    }
    __syncthreads();
    return *sflag;
}

__device__ __forceinline__ unsigned bf16r(float f) {  // fp32 -> bf16 bits, RNE
    unsigned u = __float_as_uint(f);
    return (u + 0x7FFFu + ((u >> 16) & 1u)) >> 16;
}
__device__ __forceinline__ float blo(unsigned u) { return __uint_as_float(u << 16); }
__device__ __forceinline__ float bhi(unsigned u) { return __uint_as_float(u & 0xFFFF0000u); }

// ---------- pass A: per-block LDS histogram of dst buckets ----------
__global__ void k_countA(const int* __restrict__ ei, int* __restrict__ cntRM) {
    __shared__ int h[NB];
    __shared__ int sflag;
    int tid = threadIdx.x, g = blockIdx.x;
    for (int i = tid; i < NB; i += 256) h[i] = 0;
    int is64 = detect64(ei, &sflag, tid);
    __syncthreads();
    int base = g * EPB;
    for (int e = base + tid; e < base + EPB; e += 256) {
        int dst = is64 ? ei[2 * NE + 2 * e] : ei[NE + e];
        atomicAdd(&h[dst / NPB], 1);
    }
    __syncthreads();
    for (int i = tid; i < NB; i += 256) cntRM[g * NB + i] = h[i];
}

// ---------- pass B1: per-bucket exclusive scan over fill blocks ----------
__global__ void k_scanCol(const int* __restrict__ cntRM, int* __restrict__ offsT,
                          int* __restrict__ total) {
    __shared__ int pair[256];
    int b = blockIdx.x, t = threadIdx.x;
    int a0 = cntRM[(2 * t) * NB + b];
    int a1 = cntRM[(2 * t + 1) * NB + b];
    pair[t] = a0 + a1;
    __syncthreads();
    for (int off = 1; off < 256; off <<= 1) {
        int v = (t >= off) ? pair[t - off] : 0;
        __syncthreads();
        pair[t] += v;
        __syncthreads();
    }
    int excl = pair[t] - (a0 + a1);
    offsT[b * GC + 2 * t] = excl;
    offsT[b * GC + 2 * t + 1] = excl + a0;
    if (t == 255) total[b] = pair[255];
}

// ---------- pass B2: scan bucket totals -> bucket bases ----------
__global__ void k_scanTot(const int* __restrict__ total, int* __restrict__ bbase) {
    __shared__ int s[512];
    int t = threadIdx.x;
    int v = (t < NB) ? total[t] : 0;
    s[t] = v;
    __syncthreads();
    for (int off = 1; off < 512; off <<= 1) {
        int x = (t >= off) ? s[t - off] : 0;
        __syncthreads();
        s[t] += x;
        __syncthreads();
    }
    if (t < NB) bbase[t] = s[t] - v;
    if (t == NB - 1) bbase[NB] = s[t];
}

// ---------- pass C: block-local bucket sort in LDS + fully coalesced write ----------
// edata is BLOCK-MAJOR: block g's edges at [g*EPB,(g+1)*EPB), bucket-sorted within.
// locRM[g*NB+b] = start of bucket b's run inside block g's region.
__global__ void k_fillC(const int* __restrict__ ei, const float* __restrict__ w,
                        const int* __restrict__ cntRM, int* __restrict__ locRM,
                        int2* __restrict__ edata) {
    __shared__ int2 stage[EPB];    // 50 KB
    __shared__ int hoff[NB];       // scan result, then atomic cursors
    __shared__ int pairscan[256];
    __shared__ int sflag;
    int tid = threadIdx.x, g = blockIdx.x;
    // exclusive scan of this block's histogram row (500 values, pair-per-thread)
    int i0 = 2 * tid, i1 = 2 * tid + 1;
    int a0 = (i0 < NB) ? cntRM[g * NB + i0] : 0;
    int a1 = (i1 < NB) ? cntRM[g * NB + i1] : 0;
    pairscan[tid] = a0 + a1;
    __syncthreads();
    for (int off = 1; off < 256; off <<= 1) {
        int v = (tid >= off) ? pairscan[tid - off] : 0;
        __syncthreads();
        pairscan[tid] += v;
        __syncthreads();
    }
    int excl = pairscan[tid] - (a0 + a1);
    if (i0 < NB) { hoff[i0] = excl;      locRM[g * NB + i0] = excl; }
    if (i1 < NB) { hoff[i1] = excl + a0; locRM[g * NB + i1] = excl + a0; }
    int is64 = detect64(ei, &sflag, tid);  // barrier inside also covers hoff writes
    __syncthreads();
    int base = g * EPB;
    for (int e = base + tid; e < base + EPB; e += 256) {
        int src, dst;
        if (is64) { src = ei[2 * e]; dst = ei[2 * NE + 2 * e]; }
        else      { src = ei[e];     dst = ei[NE + e]; }
        int b = dst / NPB;
        int dloc = dst - b * NPB;
        int pos = atomicAdd(&hoff[b], 1);
        stage[pos] = make_int2(src | (dloc << 20), __float_as_int(w[e]));
    }
    __syncthreads();
    const int4* so = (const int4*)stage;
    int4* go = (int4*)(edata + (size_t)g * EPB);
    for (int i = tid; i < EPB / 2; i += 256) go[i] = so[i];
}

// ---------- per-bucket segment gather + counting sort -> per-node CSR + dinv ----------
__global__ __launch_bounds__(512) void k_nodecsr(
        const int* __restrict__ cntRM, const int* __restrict__ locRM,
        const int* __restrict__ offsT, const int* __restrict__ bbase,
        const int2* __restrict__ edata, int2* __restrict__ edata2,
        int* __restrict__ rowptr, float* __restrict__ dinv) {
    __shared__ int2 stage[CAP];   // 57.3 KB
    __shared__ int cnt[NPB];
    __shared__ int offs[NPB];
    __shared__ float deg[NPB];
    __shared__ int sc[512];
    int b = blockIdx.x, tid = threadIdx.x;
    if (tid < NPB) { cnt[tid] = 0; deg[tid] = 0.f; }
    __syncthreads();
    // one segment per thread: block g's run for bucket b
    int g = tid;  // 512 threads == GC
    int len  = cntRM[g * NB + b];
    int gsrc = g * EPB + locRM[g * NB + b];
    int sdst = offsT[b * GC + g];  // within-bucket position (coalesced read)
    // phase 1: copy to LDS stage + histogram + weighted degree
    for (int k = 0; k < len; ++k) {
        int2 e = edata[gsrc + k];
        int dloc = e.x >> 20;
        atomicAdd(&cnt[dloc], 1);
        atomicAdd(&deg[dloc], __int_as_float(e.y));
        int p = sdst + k;
        if (p < CAP) stage[p] = e;
    }
    __syncthreads();
    // exclusive scan of cnt[0..NPB) over 512 slots
    int v = (tid < NPB) ? cnt[tid] : 0;
    sc[tid] = v;
    __syncthreads();
    for (int off = 1; off < 512; off <<= 1) {
        int x = (tid >= off) ? sc[tid - off] : 0;
        __syncthreads();
        sc[tid] += x;
        __syncthreads();
    }
    int s = bbase[b];
    if (tid < NPB) {
        int base = s + sc[tid] - v;
        offs[tid] = base;
        rowptr[b * NPB + tid] = base;
        dinv[b * NPB + tid] = rsqrtf(1.0f + deg[tid]);
    }
    if (b == NB - 1 && tid == 0) rowptr[NN] = bbase[NB];
    __syncthreads();
    // phase 2: counting-sort scatter (bucket-local region, ~51 KB -> amp ~1)
    for (int k = 0; k < len; ++k) {
        int p = sdst + k;
        int2 e = (p < CAP) ? stage[p] : edata[gsrc + k];
        int pos = atomicAdd(&offs[e.x >> 20], 1);
        edata2[pos] = make_int2(e.x & 0xFFFFF, e.y);
    }
}

// ---------- hs1b[n,l] = packed bf16 pair of dinv[n]*(x @ W1)[n, 2l:2l+2] ----------
__global__ void k_gemm1(const float* __restrict__ x, const float* __restrict__ W1,
                        const float* __restrict__ dinv, unsigned* __restrict__ hs1b) {
    __shared__ float Ws[FIN * FH];   // 8 KB
    __shared__ float Xs[16 * FIN];   // 4 KB
    int tid = threadIdx.x;
    for (int i = tid; i < FIN * FH; i += 256) Ws[i] = W1[i];
    int row0 = blockIdx.x * 16;
    for (int i = tid; i < 16 * FIN; i += 256) Xs[i] = x[row0 * FIN + i];
    __syncthreads();
    int l = tid & 15, r = tid >> 4;
    int n = row0 + r;
    float a0 = 0.f, a1 = 0.f;
    const float* xr = &Xs[r * FIN];
#pragma unroll
    for (int f = 0; f < FIN; ++f) {
        float xv = xr[f];
        a0 += xv * Ws[f * FH + 2 * l];
        a1 += xv * Ws[f * FH + 2 * l + 1];
    }
    float di = dinv[n];
    hs1b[n * 16 + l] = bf16r(di * a0) | (bf16r(di * a1) << 16);
}

// ---------- pull layer 1 (bf16 gathers, 16 lanes/node, ILP4) + fused gemm2 ----------
__global__ void k_pull1(const int* __restrict__ rowptr, const int2* __restrict__ ed,
                        const unsigned* __restrict__ hs1b, const float* __restrict__ dinv,
                        const float* __restrict__ b1, const float* __restrict__ W2,
                        float* __restrict__ x1out, float* __restrict__ hs2) {
    __shared__ float Ws2[FH * FO];
    int tid = threadIdx.x;
    if (tid < FH * FO) Ws2[tid] = W2[tid];
    __syncthreads();
    int l = tid & 15;
    int n = blockIdx.x * 16 + (tid >> 4);
    int s = rowptr[n], t = rowptr[n + 1];
    unsigned su = hs1b[n * 16 + l];
    float a0 = blo(su), a1 = bhi(su);  // self-loop (w=1)
    int i = s;
    for (; i + 4 <= t; i += 4) {
        int2 e0 = ed[i], e1 = ed[i + 1], e2 = ed[i + 2], e3 = ed[i + 3];
        unsigned u0 = hs1b[e0.x * 16 + l];
        unsigned u1 = hs1b[e1.x * 16 + l];
        unsigned u2 = hs1b[e2.x * 16 + l];
        unsigned u3 = hs1b[e3.x * 16 + l];
        float w0 = __int_as_float(e0.y), w1 = __int_as_float(e1.y);
        float w2 = __int_as_float(e2.y), w3 = __int_as_float(e3.y);
        a0 += w0 * blo(u0); a1 += w0 * bhi(u0);
        a0 += w1 * blo(u1); a1 += w1 * bhi(u1);
        a0 += w2 * blo(u2); a1 += w2 * bhi(u2);
        a0 += w3 * blo(u3); a1 += w3 * bhi(u3);
    }
    for (; i < t; ++i) {
        int2 e = ed[i];
        unsigned u = hs1b[e.x * 16 + l];
        float we = __int_as_float(e.y);
        a0 += we * blo(u); a1 += we * bhi(u);
    }
    float di = dinv[n];
    float v0 = di * a0 + b1[2 * l];
    float v1 = di * a1 + b1[2 * l + 1];
    v0 = (v0 > 0.f) ? v0 : 0.f;
    v1 = (v1 > 0.f) ? v1 : 0.f;
    float2 st; st.x = v0; st.y = v1;
    *(float2*)&x1out[n * FH + 2 * l] = st;
    // fused layer-2 transform: hs2[n,c] = dinv[n] * sum_h x1[n,h]*W2[h,c]  (stride 8)
#pragma unroll
    for (int c = 0; c < FO; ++c) {
        float p = v0 * Ws2[(2 * l) * FO + c] + v1 * Ws2[(2 * l + 1) * FO + c];
        p += __shfl_xor(p, 1, 16);
        p += __shfl_xor(p, 2, 16);
        p += __shfl_xor(p, 4, 16);
        p += __shfl_xor(p, 8, 16);
        if (l == c) hs2[n * 8 + c] = di * p;
    }
}

// ---------- pull layer 2: per-node, 8 lanes/node, ILP4 (hs2 padded stride 8) ----------
__global__ void k_pull2(const int* __restrict__ rowptr, const int2* __restrict__ ed,
                        const float* __restrict__ hs2, const float* __restrict__ dinv,
                        const float* __restrict__ b2, float* __restrict__ out) {
    int tid = threadIdx.x;
    int c = tid & 7;
    int cm = (c < FO) ? c : 0;
    int n = blockIdx.x * 32 + (tid >> 3);
    int s = rowptr[n], t = rowptr[n + 1];
    float acc = hs2[n * 8 + cm];  // self-loop
    int i = s;
    for (; i + 4 <= t; i += 4) {
        int2 e0 = ed[i], e1 = ed[i + 1], e2 = ed[i + 2], e3 = ed[i + 3];
        float v0 = hs2[e0.x * 8 + cm];
        float v1 = hs2[e1.x * 8 + cm];
        float v2 = hs2[e2.x * 8 + cm];
        float v3 = hs2[e3.x * 8 + cm];
        acc += __int_as_float(e0.y) * v0;
        acc += __int_as_float(e1.y) * v1;
        acc += __int_as_float(e2.y) * v2;
        acc += __int_as_float(e3.y) * v3;
    }
    for (; i < t; ++i) {
        int2 e = ed[i];
        acc += __int_as_float(e.y) * hs2[e.x * 8 + cm];
    }
    if (c < FO) out[n * FO + c] = dinv[n] * acc + b2[c];
}

extern "C" void kernel_launch(void* const* d_in, const int* in_sizes, int n_in,
                              void* d_out, int out_size, void* d_ws, size_t ws_size,
                              hipStream_t stream) {
    const float* x  = (const float*)d_in[0];
    const int*   ei = (const int*)d_in[1];
    const float* w  = (const float*)d_in[2];
    const float* W1 = (const float*)d_in[3];
    const float* b1 = (const float*)d_in[4];
    const float* W2 = (const float*)d_in[5];
    const float* b2 = (const float*)d_in[6];
    float* out = (float*)d_out;  // x2 in [0,5N), x1 in [5N,37N)
    float* ws  = (float*)d_ws;

    // workspace layout (4B words), ~55 MB:
    // [0, 6.4M)        edata (block-major, bucket-sorted within block); dead after
    //                  nodecsr -> hs1b [0,1.6M), hs2 [1.6M,2.4M) reuse it
    // [6.4M, 12.8M)    edata2 (per-node CSR order, persists through pulls)
    // [12.8M, ...)     cntRM / locRM / offsT / dinv / rowptr / bbase / total
    int2*     edata  = (int2*)ws;
    int2*     edata2 = (int2*)(ws + 6400000);
    int*      cntRM  = (int*)(ws + 12800000);            // GC*NB = 256000
    int*      locRM  = (int*)(ws + 12800000 + 256000);   // GC*NB = 256000
    int*      offsT  = (int*)(ws + 12800000 + 512000);   // GC*NB = 256000
    float*    dinv   = ws + 13600000;                    // 100k
    int*      rowptr = (int*)(ws + 13700000);            // NN+1
    int*      bbase  = (int*)(ws + 13800064);            // NB+1
    int*      total  = (int*)(ws + 13800704);            // NB
    unsigned* hs1b   = (unsigned*)ws;                    // 1.6M (edata dead by gemm1)
    float*    hs2    = ws + 1600000;                     // 800k (stride-8 padded)

    float* x1 = out + NN * FO;

    k_countA<<<GC, 256, 0, stream>>>(ei, cntRM);
    k_scanCol<<<NB, 256, 0, stream>>>(cntRM, offsT, total);
    k_scanTot<<<1, 512, 0, stream>>>(total, bbase);
    k_fillC<<<GC, 256, 0, stream>>>(ei, w, cntRM, locRM, edata);
    k_nodecsr<<<NB, 512, 0, stream>>>(cntRM, locRM, offsT, bbase, edata, edata2, rowptr, dinv);
    k_gemm1<<<NN / 16, 256, 0, stream>>>(x, W1, dinv, hs1b);
    k_pull1<<<NN / 16, 256, 0, stream>>>(rowptr, edata2, hs1b, dinv, b1, W2, x1, hs2);
    k_pull2<<<NN / 32, 256, 0, stream>>>(rowptr, edata2, hs2, dinv, b2, out);
}